// Round 3
// baseline (323.161 us; speedup 1.0000x reference)
//
#include <hip/hip_runtime.h>
#include <math.h>

// Model_7310034338114: two Flaubert/XLM MHA blocks (eval), fp32 in/out.
// inst0: x (4,1024,192), 16 heads, dph=12. inst1: y (4,1024,66), 11 heads, dph=6.
//
// Round 14: 3 kernels -> 2. oproj fused into attn via last-block gating:
// each (b, 64-row strip) output tile needs H head-strips of ctx; the attn
// block that finishes its group's last strip (device-scope atomicAdd on a
// per-group counter, producer/consumer __threadfence) immediately does that
// strip's output projection. No spin-waits -> no dispatch-order hazard.
// oproj phase uses ZERO LDS (attn occupancy preserved): W^T is pre-converted
// to f16 hi/lo in workspace by 8 aux blocks appended to the qkv grid (they
// also zero the group counters); ctx fragments are read straight from global
// with in-register hi/lo split. MFMA order is instruction-identical to r13's
// oproj -> bit-identical results. r13 calibration: ~10us per kernel boundary.

#define BS 4
#define SLEN 1024

// workspace float offsets
#define Q0_OFF 0              // f32 [4][16][1024][12]  (786432)
#define C0_OFF 786432         // f32 [4096][192]        (786432)
#define Q1_OFF 1572864        // f32 [4][11][1024][6]   (270336)
#define C1_OFF 1843200        // f32 [4096][66]         (270336)
#define K0H_OFF 2113536       // f16 [4][16][1024][12]  (786432 h = 393216 fl)
#define V0T_OFF 2506752       // f16 [4][16][12][1024]  (786432 h)
#define K1H_OFF 2899968       // f16 [4][11][1024][8]   (360448 h = 180224 fl)
#define V1T_OFF 3080192       // f16 [4][11][6][1024]   (270336 h = 135168 fl)
#define CNT_OFF 3223552       // int [8] (inst*4 + b)
#define GRP_OFF 3223560       // int [128] oproj group counters
#define WT0H_OFF 3223696      // f16 [192][192] W0^T hi (36864 h = 18432 fl)
#define WT0L_OFF 3242128      // f16 [192][192] W0^T lo
#define WT1H_OFF 3260560      // f16 [66][96]   W1^T hi (6336 h = 3168 fl)
#define WT1L_OFF 3263728      // f16 [66][96]   W1^T lo

#define OUT0_SIZE 786432      // 4096*192

#if __has_builtin(__builtin_amdgcn_exp2f)
#define EXP2(x) __builtin_amdgcn_exp2f(x)
#else
#define EXP2(x) __expf((x) * 0.69314718056f)
#endif

typedef _Float16 f16x2 __attribute__((ext_vector_type(2)));
typedef _Float16 f16x4 __attribute__((ext_vector_type(4)));
typedef _Float16 f16x8 __attribute__((ext_vector_type(8)));
typedef float f32x4 __attribute__((ext_vector_type(4)));

// ---------------------------------------------------------------------------
// f16-MFMA GEMM building block (round-4 proven): BM=BN=BK=64, 4 waves.
// ---------------------------------------------------------------------------
__device__ __forceinline__ void mfma_chunk(const _Float16* sA, const _Float16* sWT,
                                           int wv, int lane, f32x4 acc[4])
{
  const int col = lane & 15, grp = lane >> 4;
#pragma unroll
  for (int ks = 0; ks < 2; ++ks) {
    const f16x8 bf = *(const f16x8*)(sWT + (wv * 16 + col) * 72 + ks * 32 + grp * 8);
#pragma unroll
    for (int mt = 0; mt < 4; ++mt) {
      const f16x8 af = *(const f16x8*)(sA + (mt * 16 + col) * 72 + ks * 32 + grp * 8);
      acc[mt] = __builtin_amdgcn_mfma_f32_16x16x32_f16(af, bf, acc[mt], 0, 0, 0);
    }
  }
}

// ---------------------------------------------------------------------------
// QKV projection + integrated mask scan (r13, unchanged).
// ---------------------------------------------------------------------------
template <int DIM, int H, int DPH, int NT, int NCH, int KST>
__device__ void qkv_impl(int bid, const float* __restrict__ X,
                         const int* __restrict__ mask,
                         const float* __restrict__ qw, const float* __restrict__ qb,
                         const float* __restrict__ kw, const float* __restrict__ kb,
                         const float* __restrict__ vw, const float* __restrict__ vb,
                         float* __restrict__ qo, _Float16* __restrict__ kh,
                         _Float16* __restrict__ vth, int* __restrict__ cnt_out,
                         char* smem)
{
  const int mt64 = bid & 63;
  const int rest = bid >> 6;
  const int mat = rest / NT;
  const int nt = rest % NT;
  const int row0 = mt64 * 64, col0 = nt * 64;

  const float* W = (mat == 0) ? qw : (mat == 1) ? kw : vw;
  const float* B = (mat == 0) ? qb : (mat == 1) ? kb : vb;
  const float scale = (mat == 0) ? (1.44269504089f / sqrtf((float)DPH)) : 1.0f;

  _Float16* sA = (_Float16*)smem;            // 64*72 halves
  _Float16* sWT = sA + 64 * 72;              // 64*72 halves
  int* sSP = (int*)(smem + 2 * 64 * 72 * 2); // 64 ints, persists to epilogue

  const int tid = threadIdx.x;
  const int wv = tid >> 6, lane = tid & 63;

  // register-staged prefetch (global->reg) / commit (reg->LDS as f16)
  float2 rA[8], rW[8];
  auto qprefetch = [&](int c) {
    const int kc = c * 64;
#pragma unroll
    for (int t = 0; t < 8; ++t) {
      const int idx = tid + t * 256;
      {
        const int m = idx >> 5, k = (idx & 31) * 2;
        rA[t] = (kc + k < DIM)
                    ? *(const float2*)(X + (size_t)(row0 + m) * DIM + kc + k)
                    : make_float2(0.f, 0.f);
      }
      {
        const int k = idx >> 5, n = (idx & 31) * 2;
        rW[t] = (kc + k < DIM && col0 + n < DIM)
                    ? *(const float2*)(W + (size_t)(kc + k) * DIM + col0 + n)
                    : make_float2(0.f, 0.f);
      }
    }
  };
  auto qcommit = [&]() {
#pragma unroll
    for (int t = 0; t < 8; ++t) {
      const int idx = tid + t * 256;
      {
        const int m = idx >> 5, k = (idx & 31) * 2;
        *(f16x2*)(sA + m * 72 + k) = (f16x2){(_Float16)rA[t].x, (_Float16)rA[t].y};
      }
      {
        const int k = idx >> 5, n = (idx & 31) * 2;
        sWT[n * 72 + k] = (_Float16)rW[t].x;
        sWT[(n + 1) * 72 + k] = (_Float16)rW[t].y;
      }
    }
  };

  qprefetch(0);   // issue chunk-0 loads first; scan below runs under their latency

  // ---- in-block mask scan (K/V blocks only): sSP[j] = slot of row row0+j ----
  if (mat != 0) {
    int* sS = (int*)smem;          // aliases sA: used strictly before staging
    const int b = row0 >> 10;
    const int* m = mask + (b << 10);
    int mv[4], s4 = 0;
#pragma unroll
    for (int i = 0; i < 4; ++i) { mv[i] = m[tid * 4 + i] ? 1 : 0; s4 += mv[i]; }
    sS[tid] = s4;
    __syncthreads();
    for (int off = 1; off < 256; off <<= 1) {   // Hillis-Steele inclusive scan
      const int v = sS[tid];
      const int add = (tid >= off) ? sS[tid - off] : 0;
      __syncthreads();
      sS[tid] = v + add;
      __syncthreads();
    }
    const int tot = sS[255];
    int u = tid ? sS[tid - 1] : 0;   // unmasked count before this thread's span
    const int s0 = row0 & 1023;
#pragma unroll
    for (int i = 0; i < 4; ++i) {
      const int s = tid * 4 + i;
      const int sp = mv[i] ? u : tot + (s - u);
      u += mv[i];
      const unsigned rel = (unsigned)(s - s0);
      if (rel < 64u) sSP[rel] = sp;
    }
    if (mat == 1 && nt == 0 && s0 == 0 && tid == 0) cnt_out[b] = tot;
    __syncthreads();   // sSP visible; sS region free for staging
  }

  f32x4 acc[4] = {{0.f,0.f,0.f,0.f},{0.f,0.f,0.f,0.f},{0.f,0.f,0.f,0.f},{0.f,0.f,0.f,0.f}};

  for (int c = 0; c < NCH; ++c) {
    __syncthreads();                 // previous mfma done reading LDS
    qcommit();
    __syncthreads();
    if (c + 1 < NCH) qprefetch(c + 1);   // loads overlap this chunk's MFMA
    mfma_chunk(sA, sWT, wv, lane, acc);
  }

  const int col = lane & 15, grp = lane >> 4;
  const int cidx = col0 + wv * 16 + col;
  if (cidx < DIM) {
    const float bias = B[cidx];
    const int h = cidx / DPH, d = cidx % DPH;
#pragma unroll
    for (int mt = 0; mt < 4; ++mt) {
#pragma unroll
      for (int r = 0; r < 4; ++r) {
        const int m = row0 + mt * 16 + grp * 4 + r;
        const int b = m >> 10, s = m & 1023;
        const float v = acc[mt][r] + bias;
        const int bh = b * H + h;
        if (mat == 0) {
          qo[(size_t)((bh << 10) + s) * DPH + d] = v * scale;
        } else {
          const int sp = sSP[mt * 16 + grp * 4 + r];
          if (mat == 1)
            kh[(size_t)((bh << 10) + sp) * KST + d] = (_Float16)v;
          else
            vth[((size_t)(bh * DPH + d) << 10) + sp] = (_Float16)v;
        }
      }
    }
  }
}

// ---------------------------------------------------------------------------
// Aux blocks (appended to qkv grid): zero oproj group counters and convert
// o0w/o1w into f16 hi/lo W^T arrays (zero k-padding) for the fused oproj.
// ---------------------------------------------------------------------------
__device__ void qkv_aux(int aid, const float* __restrict__ o0w,
                        const float* __restrict__ o1w,
                        _Float16* __restrict__ wt0h, _Float16* __restrict__ wt0l,
                        _Float16* __restrict__ wt1h, _Float16* __restrict__ wt1l,
                        int* __restrict__ grp)
{
  const int tid = threadIdx.x;
  if (aid == 0 && tid < 128) grp[tid] = 0;
  if (aid < 6) {          // inst0: 192 x 192, 6144 elems per block
    for (int e = aid * 6144 + tid; e < (aid + 1) * 6144; e += 256) {
      const int n = e / 192, k = e - n * 192;
      const float v = o0w[k * 192 + n];        // W^T[n][k] = W[k][n]
      const _Float16 h = (_Float16)v;
      wt0h[n * 192 + k] = h;
      wt0l[n * 192 + k] = (_Float16)(v - (float)h);
    }
  } else {                // inst1: 66 x 96 (k padded to 96), 3168 per block
    const int a = aid - 6;
    for (int e = a * 3168 + tid; e < (a + 1) * 3168; e += 256) {
      const int n = e / 96, k = e - n * 96;
      const float v = (k < 66) ? o1w[k * 66 + n] : 0.f;
      const _Float16 h = (_Float16)v;
      wt1h[n * 96 + k] = h;
      wt1l[n * 96 + k] = (_Float16)(v - (float)h);
    }
  }
}

__global__ __launch_bounds__(256) void qkv_kernel(
    const float* __restrict__ x, const float* __restrict__ y,
    const int* __restrict__ mask0, const int* __restrict__ mask1,
    const float* __restrict__ q0w, const float* __restrict__ q0b,
    const float* __restrict__ k0w, const float* __restrict__ k0b,
    const float* __restrict__ v0w, const float* __restrict__ v0b,
    const float* __restrict__ q1w, const float* __restrict__ q1b,
    const float* __restrict__ k1w, const float* __restrict__ k1b,
    const float* __restrict__ v1w, const float* __restrict__ v1b,
    const float* __restrict__ o0w, const float* __restrict__ o1w,
    float* __restrict__ ws)
{
  extern __shared__ char smem[];
  _Float16* hws = (_Float16*)ws;
  int* cnts = (int*)(ws + CNT_OFF);
  const int bid = blockIdx.x;
  if (bid >= 960) {
    qkv_aux(bid - 960, o0w, o1w,
            hws + 2 * (size_t)WT0H_OFF, hws + 2 * (size_t)WT0L_OFF,
            hws + 2 * (size_t)WT1H_OFF, hws + 2 * (size_t)WT1L_OFF,
            (int*)(ws + GRP_OFF));
    return;
  }
  if (bid < 576)   // 64 mtiles * 3 mats * 3 ntiles
    qkv_impl<192, 16, 12, 3, 3, 12>(bid, x, mask0, q0w, q0b, k0w, k0b, v0w, v0b,
                                    ws + Q0_OFF, hws + 2 * (size_t)K0H_OFF,
                                    hws + 2 * (size_t)V0T_OFF, cnts, smem);
  else             // 64 * 3 * 2 = 384
    qkv_impl<66, 11, 6, 2, 2, 8>(bid - 576, y, mask1, q1w, q1b, k1w, k1b, v1w, v1b,
                                 ws + Q1_OFF, hws + 2 * (size_t)K1H_OFF,
                                 hws + 2 * (size_t)V1T_OFF, cnts + 4, smem);
}

// ---------------------------------------------------------------------------
// Attention (r11-proven S^T trick) + fused output projection (last block of
// each (b,strip) group). oproj phase: zero LDS, W^T f16 hi/lo from global,
// ctx fragments from global with in-register hi/lo split; MFMA order
// instruction-identical to r13's oproj.
// ---------------------------------------------------------------------------
template <int H, int DPH, int SKP, int DIMo, int NT, int NKB, int KP, bool VEC>
__device__ void attn_impl(int bid, const float* __restrict__ qg,
                          const _Float16* __restrict__ kh,
                          const _Float16* __restrict__ vth,
                          const int* __restrict__ cnts,
                          float* __restrict__ ctx,
                          const _Float16* __restrict__ WTh,
                          const _Float16* __restrict__ WTl,
                          const float* __restrict__ obias,
                          float* __restrict__ outp,
                          int* __restrict__ grp, int gbase, char* smem)
{
  constexpr int CH = 128;              // keys per chunk
  constexpr int KBUF = CH * SKP + 32;  // +32: kf reads reach key*SKP+15
  constexpr int VST = 136;             // V^T row stride (halves)

  _Float16* sK = (_Float16*)smem;                 // 2 x KBUF
  _Float16* sVT = sK + 2 * KBUF;                  // 2 x DPH*VST

  const int bh = bid >> 4;             // 16 strips per bh
  const int b = bh / H;
  const int h = bh % H;
  const int tid = threadIdx.x;

  const float* qb_ = qg + (size_t)bh * SLEN * DPH;
  const _Float16* kb_ = kh + (size_t)bh * SLEN * SKP;
  const _Float16* vb_ = vth + ((size_t)bh * DPH << 10);
  const int cnt = cnts[b];
  const int nch = (cnt + CH - 1) >> 7;   // dynamic chunk count (1..8)

  // zero the 32-half tails of both sK buffers (never rewritten by commit)
  if (tid < 64) sK[(tid >> 5) * KBUF + CH * SKP + (tid & 31)] = (_Float16)0.f;

  const int wave = tid >> 6, lane = tid & 63;
  const int col = lane & 15, grpq = lane >> 4;
  const int qtile = (bid & 15) * 4 + wave;   // 16-row q-tile index

  // Q fragment, B-operand layout: B[k=d=grp*4+j][n=qrow=col], zero-padded
  f16x4 aq;
  {
    const int qrow = qtile * 16 + col;
#pragma unroll
    for (int j = 0; j < 4; ++j) {
      const int d = grpq * 4 + j;
      aq[j] = (d < DPH) ? (_Float16)qb_[(size_t)qrow * DPH + d] : (_Float16)0.f;
    }
  }

  // register-staged prefetch / LDS commit
  constexpr int kN = CH * SKP / 8;     // uint4 count for K
  constexpr int vN = DPH * 16;         // uint4 count for V
  const int vd = tid >> 4, vq = tid & 15;
  uint4 pk, pv;
  auto prefetch = [&](int cc) {
    if (tid < kN) pk = ((const uint4*)(kb_ + (size_t)cc * CH * SKP))[tid];
    if (tid < vN) pv = ((const uint4*)(vb_ + ((size_t)vd << 10) + cc * CH))[vq];
  };
  auto commit = [&](int pb) {
    if (tid < kN) ((uint4*)(sK + pb * KBUF))[tid] = pk;
    if (tid < vN) *(uint4*)(sVT + (pb * DPH + vd) * VST + vq * 8) = pv;
  };

  prefetch(0);
  commit(0);
  __syncthreads();

  f32x4 Oacc[2] = {{0.f,0.f,0.f,0.f},{0.f,0.f,0.f,0.f}};
  float lsum = 0.f;
  const int de = (col < DPH) ? col : 0;   // clamped: cols >= DPH discarded

#pragma unroll 1
  for (int c = 0; c < nch; ++c) {
    const int p = c & 1;
    if (c + 1 < nch) prefetch(c + 1);

    const _Float16* sKp = sK + p * KBUF;
    const _Float16* sVp = sVT + p * DPH * VST;
    const int keyr = c * CH + grpq * 4;   // this lane's reg-dim key base

#pragma unroll
    for (int kt = 0; kt < CH / 16; ++kt) {
      const f16x4 kf = *(const f16x4*)(sKp + (kt * 16 + col) * SKP + grpq * 4);
      const int k0 = keyr + kt * 16;
      const f32x4 biasv = {(k0 < cnt) ? 0.f : -100.f,
                           (k0 + 1 < cnt) ? 0.f : -100.f,
                           (k0 + 2 < cnt) ? 0.f : -100.f,
                           (k0 + 3 < cnt) ? 0.f : -100.f};
      const f32x4 S = __builtin_amdgcn_mfma_f32_16x16x16f16(kf, aq, biasv,
                                                            0, 0, 0);
      const float e0 = EXP2(S[0]), e1 = EXP2(S[1]);
      const float e2 = EXP2(S[2]), e3 = EXP2(S[3]);
      lsum += (e0 + e1) + (e2 + e3);
      const f16x4 pf = {(_Float16)e0, (_Float16)e1, (_Float16)e2, (_Float16)e3};
      const f16x4 vf = *(const f16x4*)(sVp + de * VST + kt * 16 + grpq * 4);
      Oacc[kt & 1] = __builtin_amdgcn_mfma_f32_16x16x16f16(pf, vf, Oacc[kt & 1],
                                                           0, 0, 0);
    }

    if (c + 1 < nch) commit(p ^ 1);
    __syncthreads();
  }

  // epilogue — ALL cross-lane ops unconditional (r5's NaN was divergence here)
  f32x4 Osum;
#pragma unroll
  for (int r = 0; r < 4; ++r) Osum[r] = Oacc[0][r] + Oacc[1][r];
  float lred = lsum;
  lred += __shfl_xor(lred, 16);
  lred += __shfl_xor(lred, 32);            // lred = l(qrow=col), all lanes
  float lq[4];
#pragma unroll
  for (int r = 0; r < 4; ++r) lq[r] = __shfl(lred, grpq * 4 + r);
  if (col < DPH) {
    const int qrow0 = qtile * 16;
#pragma unroll
    for (int r = 0; r < 4; ++r) {
      const int row = qrow0 + grpq * 4 + r;
      ctx[(size_t)(b * SLEN + row) * (H * DPH) + h * DPH + col] = Osum[r] / lq[r];
    }
  }

  // ---- fused oproj: last finisher of group (b,strip) projects 64 rows ----
  __threadfence();                 // release this block's ctx stores (all thr)
  __syncthreads();
  int* flag = (int*)smem;          // LDS free after the sync above
  if (tid == 0) {
    const int g = gbase + b * 16 + (bid & 15);
    flag[0] = (atomicAdd(&grp[g], 1) == H - 1) ? 1 : 0;
  }
  __syncthreads();
  if (!flag[0]) return;
  __threadfence();                 // acquire: drop stale cached ctx lines

  const int strip = bid & 15;
  const float* Crow = ctx + (size_t)(b * SLEN + strip * 64) * DIMo;
  float* Orow = outp + (size_t)(b * SLEN + strip * 64) * DIMo;

#pragma unroll 1
  for (int nt = 0; nt < NT; ++nt) {
    const int cidx = nt * 64 + wave * 16 + col;
    f32x4 oacc[4] = {{0.f,0.f,0.f,0.f},{0.f,0.f,0.f,0.f},
                     {0.f,0.f,0.f,0.f},{0.f,0.f,0.f,0.f}};
#pragma unroll
    for (int kb = 0; kb < NKB; ++kb) {
      const int k0 = kb * 32 + grpq * 8;
      f16x8 bhf = {}, blf = {};
      if (cidx < DIMo) {
        bhf = *(const f16x8*)(WTh + (size_t)cidx * KP + k0);
        blf = *(const f16x8*)(WTl + (size_t)cidx * KP + k0);
      }
#pragma unroll
      for (int mt = 0; mt < 4; ++mt) {
        const int row_a = mt * 16 + col;
        f16x8 ah, al;
        if (VEC) {
          const float* ap = Crow + (size_t)row_a * DIMo + k0;
          const f32x4 v0 = *(const f32x4*)(ap);
          const f32x4 v1 = *(const f32x4*)(ap + 4);
#pragma unroll
          for (int j = 0; j < 4; ++j) {
            const _Float16 h0 = (_Float16)v0[j];
            ah[j] = h0; al[j] = (_Float16)(v0[j] - (float)h0);
            const _Float16 h1 = (_Float16)v1[j];
            ah[4 + j] = h1; al[4 + j] = (_Float16)(v1[j] - (float)h1);
          }
        } else {
#pragma unroll
          for (int j = 0; j < 8; ++j) {
            const int k = k0 + j;
            const float v = (k < DIMo) ? Crow[(size_t)row_a * DIMo + k] : 0.f;
            const _Float16 hh = (_Float16)v;
            ah[j] = hh; al[j] = (_Float16)(v - (float)hh);
          }
        }
        oacc[mt] = __builtin_amdgcn_mfma_f32_16x16x32_f16(ah, bhf, oacc[mt], 0, 0, 0);
        oacc[mt] = __builtin_amdgcn_mfma_f32_16x16x32_f16(ah, blf, oacc[mt], 0, 0, 0);
        oacc[mt] = __builtin_amdgcn_mfma_f32_16x16x32_f16(al, bhf, oacc[mt], 0, 0, 0);
      }
    }
    if (cidx < DIMo) {
      const float bias = obias[cidx];
#pragma unroll
      for (int mt = 0; mt < 4; ++mt)
#pragma unroll
        for (int r = 0; r < 4; ++r)
          Orow[(size_t)(mt * 16 + grpq * 4 + r) * DIMo + cidx] = oacc[mt][r] + bias;
    }
  }
}

__global__ __launch_bounds__(256) void attn_kernel(
    float* __restrict__ ws, float* __restrict__ out,
    const float* __restrict__ o0b, const float* __restrict__ o1b)
{
  extern __shared__ char smem[];
  _Float16* hws = (_Float16*)ws;
  const int* cnts = (const int*)(ws + CNT_OFF);
  int* grp = (int*)(ws + GRP_OFF);
  const int bid = blockIdx.x;
  if (bid < 1024)  // 64 bh * 16 q-strips
    attn_impl<16, 12, 12, 192, 3, 6, 192, true>(
        bid, ws + Q0_OFF, hws + 2 * (size_t)K0H_OFF, hws + 2 * (size_t)V0T_OFF,
        cnts, ws + C0_OFF, hws + 2 * (size_t)WT0H_OFF, hws + 2 * (size_t)WT0L_OFF,
        o0b, out, grp, 0, smem);
  else             // 44 bh * 16 = 704
    attn_impl<11, 6, 8, 66, 2, 3, 96, false>(
        bid - 1024, ws + Q1_OFF, hws + 2 * (size_t)K1H_OFF,
        hws + 2 * (size_t)V1T_OFF, cnts + 4, ws + C1_OFF,
        hws + 2 * (size_t)WT1H_OFF, hws + 2 * (size_t)WT1L_OFF,
        o1b, out + OUT0_SIZE, grp, 64, smem);
}

// ---------------------------------------------------------------------------
extern "C" void kernel_launch(void* const* d_in, const int* in_sizes, int n_in,
                              void* d_out, int out_size, void* d_ws, size_t ws_size,
                              hipStream_t stream)
{
  const float* x = (const float*)d_in[0];
  const float* y = (const float*)d_in[1];
  const int* mask0 = (const int*)d_in[2];
  const int* mask1 = (const int*)d_in[3];
  const float* q0w = (const float*)d_in[4];  const float* q0b = (const float*)d_in[5];
  const float* k0w = (const float*)d_in[6];  const float* k0b = (const float*)d_in[7];
  const float* v0w = (const float*)d_in[8];  const float* v0b = (const float*)d_in[9];
  const float* o0w = (const float*)d_in[10]; const float* o0b = (const float*)d_in[11];
  const float* q1w = (const float*)d_in[12]; const float* q1b = (const float*)d_in[13];
  const float* k1w = (const float*)d_in[14]; const float* k1b = (const float*)d_in[15];
  const float* v1w = (const float*)d_in[16]; const float* v1b = (const float*)d_in[17];
  const float* o1w = (const float*)d_in[18]; const float* o1b = (const float*)d_in[19];

  float* ws = (float*)d_ws;
  float* out = (float*)d_out;

  const int qkv_smem = 2 * 64 * 72 * 2 + 64 * 4;   // 18688 B (staging + sSP)
  // attn: sK 2*(128*12+32)*2 = 6272 + sVT 2*12*136*2 = 6528 -> 12800 B
  const int attn_smem = 2 * (128 * 12 + 32) * 2 + 2 * 12 * 136 * 2;

  qkv_kernel<<<968, 256, qkv_smem, stream>>>(x, y, mask0, mask1,
                                             q0w, q0b, k0w, k0b, v0w, v0b,
                                             q1w, q1b, k1w, k1b, v1w, v1b,
                                             o0w, o1w, ws);
  attn_kernel<<<1728, 256, attn_smem, stream>>>(ws, out, o0b, o1b);
}

// Round 4
// 141.329 us; speedup vs baseline: 2.2866x; 2.2866x over previous
//
#include <hip/hip_runtime.h>
#include <math.h>

// Model_7310034338114: two Flaubert/XLM MHA blocks (eval), fp32 in/out.
// inst0: x (4,1024,192), 16 heads, dph=12. inst1: y (4,1024,66), 11 heads, dph=6.
//
// Round 15 = r13 (proven 144us) + ONE experiment: attn grid 1728 -> 1024
// blocks that grid-stride over the 1728 items (2 items for blocks 0..703).
// Distinguishes WG-dispatch/ramp cost (faster) from per-block latency with
// full co-residency (slower).
//
// Lessons banked from failed rounds:
//   r12: cooperative grid.sync on 8 non-coherent XCD L2s ~ 100us-class; a
//        kernel boundary IS the cheap device-wide barrier (~10-12us).
//   r14: (a) fusing a cold tail into a hot kernel inflates VGPR for all
//        blocks (68->128, occupancy halved); (b) per-block device-scope
//        __threadfence = L2 writeback storm (1728 fences ~ 217us). Do not
//        attempt cross-XCD producer/consumer fusion inside one kernel.

#define BS 4
#define SLEN 1024

// workspace float offsets
#define Q0_OFF 0              // f32 [4][16][1024][12]  (786432)
#define C0_OFF 786432         // f32 [4096][192]        (786432)
#define Q1_OFF 1572864        // f32 [4][11][1024][6]   (270336)
#define C1_OFF 1843200        // f32 [4096][66]         (270336)
#define K0H_OFF 2113536       // f16 [4][16][1024][12]  (786432 h = 393216 fl)
#define V0T_OFF 2506752       // f16 [4][16][12][1024]  (786432 h)
#define K1H_OFF 2899968       // f16 [4][11][1024][8]   (360448 h = 180224 fl)
#define V1T_OFF 3080192       // f16 [4][11][6][1024]   (270336 h = 135168 fl)
#define CNT_OFF 3223552       // int [8] (inst*4 + b)

#define OUT0_SIZE 786432      // 4096*192

#if __has_builtin(__builtin_amdgcn_exp2f)
#define EXP2(x) __builtin_amdgcn_exp2f(x)
#else
#define EXP2(x) __expf((x) * 0.69314718056f)
#endif

typedef _Float16 f16x2 __attribute__((ext_vector_type(2)));
typedef _Float16 f16x4 __attribute__((ext_vector_type(4)));
typedef _Float16 f16x8 __attribute__((ext_vector_type(8)));
typedef float f32x4 __attribute__((ext_vector_type(4)));

// ---------------------------------------------------------------------------
// f16-MFMA GEMM building blocks (round-4 proven): BM=BN=BK=64, 4 waves.
// ---------------------------------------------------------------------------
__device__ __forceinline__ void mfma_chunk(const _Float16* sA, const _Float16* sWT,
                                           int wv, int lane, f32x4 acc[4])
{
  const int col = lane & 15, grp = lane >> 4;
#pragma unroll
  for (int ks = 0; ks < 2; ++ks) {
    const f16x8 bf = *(const f16x8*)(sWT + (wv * 16 + col) * 72 + ks * 32 + grp * 8);
#pragma unroll
    for (int mt = 0; mt < 4; ++mt) {
      const f16x8 af = *(const f16x8*)(sA + (mt * 16 + col) * 72 + ks * 32 + grp * 8);
      acc[mt] = __builtin_amdgcn_mfma_f32_16x16x32_f16(af, bf, acc[mt], 0, 0, 0);
    }
  }
}

__device__ __forceinline__ void mfma_chunk_split(
    const _Float16* sAh, const _Float16* sAl,
    const _Float16* sWTh, const _Float16* sWTl,
    int wv, int lane, f32x4 acc[4])
{
  const int col = lane & 15, grp = lane >> 4;
#pragma unroll
  for (int ks = 0; ks < 2; ++ks) {
    const int boff = (wv * 16 + col) * 72 + ks * 32 + grp * 8;
    const f16x8 bh = *(const f16x8*)(sWTh + boff);
    const f16x8 bl = *(const f16x8*)(sWTl + boff);
#pragma unroll
    for (int mt = 0; mt < 4; ++mt) {
      const int aoff = (mt * 16 + col) * 72 + ks * 32 + grp * 8;
      const f16x8 ah = *(const f16x8*)(sAh + aoff);
      const f16x8 al = *(const f16x8*)(sAl + aoff);
      acc[mt] = __builtin_amdgcn_mfma_f32_16x16x32_f16(ah, bh, acc[mt], 0, 0, 0);
      acc[mt] = __builtin_amdgcn_mfma_f32_16x16x32_f16(ah, bl, acc[mt], 0, 0, 0);
      acc[mt] = __builtin_amdgcn_mfma_f32_16x16x32_f16(al, bh, acc[mt], 0, 0, 0);
    }
  }
}

// ---------------------------------------------------------------------------
// QKV projection + integrated mask scan (r13, unchanged).
// ---------------------------------------------------------------------------
template <int DIM, int H, int DPH, int NT, int NCH, int KST>
__device__ void qkv_impl(int bid, const float* __restrict__ X,
                         const int* __restrict__ mask,
                         const float* __restrict__ qw, const float* __restrict__ qb,
                         const float* __restrict__ kw, const float* __restrict__ kb,
                         const float* __restrict__ vw, const float* __restrict__ vb,
                         float* __restrict__ qo, _Float16* __restrict__ kh,
                         _Float16* __restrict__ vth, int* __restrict__ cnt_out,
                         char* smem)
{
  const int mt64 = bid & 63;
  const int rest = bid >> 6;
  const int mat = rest / NT;
  const int nt = rest % NT;
  const int row0 = mt64 * 64, col0 = nt * 64;

  const float* W = (mat == 0) ? qw : (mat == 1) ? kw : vw;
  const float* B = (mat == 0) ? qb : (mat == 1) ? kb : vb;
  const float scale = (mat == 0) ? (1.44269504089f / sqrtf((float)DPH)) : 1.0f;

  _Float16* sA = (_Float16*)smem;            // 64*72 halves
  _Float16* sWT = sA + 64 * 72;              // 64*72 halves
  int* sSP = (int*)(smem + 2 * 64 * 72 * 2); // 64 ints, persists to epilogue

  const int tid = threadIdx.x;
  const int wv = tid >> 6, lane = tid & 63;

  // register-staged prefetch (global->reg) / commit (reg->LDS as f16)
  float2 rA[8], rW[8];
  auto qprefetch = [&](int c) {
    const int kc = c * 64;
#pragma unroll
    for (int t = 0; t < 8; ++t) {
      const int idx = tid + t * 256;
      {
        const int m = idx >> 5, k = (idx & 31) * 2;
        rA[t] = (kc + k < DIM)
                    ? *(const float2*)(X + (size_t)(row0 + m) * DIM + kc + k)
                    : make_float2(0.f, 0.f);
      }
      {
        const int k = idx >> 5, n = (idx & 31) * 2;
        rW[t] = (kc + k < DIM && col0 + n < DIM)
                    ? *(const float2*)(W + (size_t)(kc + k) * DIM + col0 + n)
                    : make_float2(0.f, 0.f);
      }
    }
  };
  auto qcommit = [&]() {
#pragma unroll
    for (int t = 0; t < 8; ++t) {
      const int idx = tid + t * 256;
      {
        const int m = idx >> 5, k = (idx & 31) * 2;
        *(f16x2*)(sA + m * 72 + k) = (f16x2){(_Float16)rA[t].x, (_Float16)rA[t].y};
      }
      {
        const int k = idx >> 5, n = (idx & 31) * 2;
        sWT[n * 72 + k] = (_Float16)rW[t].x;
        sWT[(n + 1) * 72 + k] = (_Float16)rW[t].y;
      }
    }
  };

  qprefetch(0);   // issue chunk-0 loads first; scan below runs under their latency

  // ---- in-block mask scan (K/V blocks only): sSP[j] = slot of row row0+j ----
  if (mat != 0) {
    int* sS = (int*)smem;          // aliases sA: used strictly before staging
    const int b = row0 >> 10;
    const int* m = mask + (b << 10);
    int mv[4], s4 = 0;
#pragma unroll
    for (int i = 0; i < 4; ++i) { mv[i] = m[tid * 4 + i] ? 1 : 0; s4 += mv[i]; }
    sS[tid] = s4;
    __syncthreads();
    for (int off = 1; off < 256; off <<= 1) {   // Hillis-Steele inclusive scan
      const int v = sS[tid];
      const int add = (tid >= off) ? sS[tid - off] : 0;
      __syncthreads();
      sS[tid] = v + add;
      __syncthreads();
    }
    const int tot = sS[255];
    int u = tid ? sS[tid - 1] : 0;   // unmasked count before this thread's span
    const int s0 = row0 & 1023;
#pragma unroll
    for (int i = 0; i < 4; ++i) {
      const int s = tid * 4 + i;
      const int sp = mv[i] ? u : tot + (s - u);
      u += mv[i];
      const unsigned rel = (unsigned)(s - s0);
      if (rel < 64u) sSP[rel] = sp;
    }
    if (mat == 1 && nt == 0 && s0 == 0 && tid == 0) cnt_out[b] = tot;
    __syncthreads();   // sSP visible; sS region free for staging
  }

  f32x4 acc[4] = {{0.f,0.f,0.f,0.f},{0.f,0.f,0.f,0.f},{0.f,0.f,0.f,0.f},{0.f,0.f,0.f,0.f}};

  for (int c = 0; c < NCH; ++c) {
    __syncthreads();                 // previous mfma done reading LDS
    qcommit();
    __syncthreads();
    if (c + 1 < NCH) qprefetch(c + 1);   // loads overlap this chunk's MFMA
    mfma_chunk(sA, sWT, wv, lane, acc);
  }

  const int col = lane & 15, grp = lane >> 4;
  const int cidx = col0 + wv * 16 + col;
  if (cidx < DIM) {
    const float bias = B[cidx];
    const int h = cidx / DPH, d = cidx % DPH;
#pragma unroll
    for (int mt = 0; mt < 4; ++mt) {
#pragma unroll
      for (int r = 0; r < 4; ++r) {
        const int m = row0 + mt * 16 + grp * 4 + r;
        const int b = m >> 10, s = m & 1023;
        const float v = acc[mt][r] + bias;
        const int bh = b * H + h;
        if (mat == 0) {
          qo[(size_t)((bh << 10) + s) * DPH + d] = v * scale;
        } else {
          const int sp = sSP[mt * 16 + grp * 4 + r];
          if (mat == 1)
            kh[(size_t)((bh << 10) + sp) * KST + d] = (_Float16)v;
          else
            vth[((size_t)(bh * DPH + d) << 10) + sp] = (_Float16)v;
        }
      }
    }
  }
}

__global__ __launch_bounds__(256) void qkv_kernel(
    const float* __restrict__ x, const float* __restrict__ y,
    const int* __restrict__ mask0, const int* __restrict__ mask1,
    const float* __restrict__ q0w, const float* __restrict__ q0b,
    const float* __restrict__ k0w, const float* __restrict__ k0b,
    const float* __restrict__ v0w, const float* __restrict__ v0b,
    const float* __restrict__ q1w, const float* __restrict__ q1b,
    const float* __restrict__ k1w, const float* __restrict__ k1b,
    const float* __restrict__ v1w, const float* __restrict__ v1b,
    float* __restrict__ ws)
{
  extern __shared__ char smem[];
  _Float16* hws = (_Float16*)ws;
  int* cnts = (int*)(ws + CNT_OFF);
  const int bid = blockIdx.x;
  if (bid < 576)   // 64 mtiles * 3 mats * 3 ntiles
    qkv_impl<192, 16, 12, 3, 3, 12>(bid, x, mask0, q0w, q0b, k0w, k0b, v0w, v0b,
                                    ws + Q0_OFF, hws + 2 * (size_t)K0H_OFF,
                                    hws + 2 * (size_t)V0T_OFF, cnts, smem);
  else             // 64 * 3 * 2 = 384
    qkv_impl<66, 11, 6, 2, 2, 8>(bid - 576, y, mask1, q1w, q1b, k1w, k1b, v1w, v1b,
                                 ws + Q1_OFF, hws + 2 * (size_t)K1H_OFF,
                                 hws + 2 * (size_t)V1T_OFF, cnts + 4, smem);
}

// ---------------------------------------------------------------------------
// Attention v11 (r11-proven internals) — S^T trick on mfma_f32_16x16x16f16
// over compacted keys. Item = (bh, 64-row q-strip), 4 waves x 16 rows.
// LDS reuse across items is safe: an item's first LDS write happens after the
// previous item's final __syncthreads (last LDS reads precede that barrier;
// after it only registers + global stores are touched).
// ---------------------------------------------------------------------------
template <int H, int DPH, int SKP>
__device__ void attn_impl(int bid, const float* __restrict__ qg,
                          const _Float16* __restrict__ kh,
                          const _Float16* __restrict__ vth,
                          const int* __restrict__ cnts,
                          float* __restrict__ ctx, char* smem)
{
  constexpr int CH = 128;              // keys per chunk
  constexpr int KBUF = CH * SKP + 32;  // +32: kf reads reach key*SKP+15
  constexpr int VST = 136;             // V^T row stride (halves)

  _Float16* sK = (_Float16*)smem;                 // 2 x KBUF
  _Float16* sVT = sK + 2 * KBUF;                  // 2 x DPH*VST

  const int bh = bid >> 4;             // 16 strips per bh
  const int b = bh / H;
  const int h = bh % H;
  const int tid = threadIdx.x;

  const float* qb_ = qg + (size_t)bh * SLEN * DPH;
  const _Float16* kb_ = kh + (size_t)bh * SLEN * SKP;
  const _Float16* vb_ = vth + ((size_t)bh * DPH << 10);
  const int cnt = cnts[b];
  const int nch = (cnt + CH - 1) >> 7;   // dynamic chunk count (1..8)

  // zero the 32-half tails of both sK buffers (never rewritten by commit)
  if (tid < 64) sK[(tid >> 5) * KBUF + CH * SKP + (tid & 31)] = (_Float16)0.f;

  const int wave = tid >> 6, lane = tid & 63;
  const int col = lane & 15, grp = lane >> 4;
  const int qtile = (bid & 15) * 4 + wave;   // 16-row q-tile index

  // Q fragment, B-operand layout: B[k=d=grp*4+j][n=qrow=col], zero-padded
  f16x4 aq;
  {
    const int qrow = qtile * 16 + col;
#pragma unroll
    for (int j = 0; j < 4; ++j) {
      const int d = grp * 4 + j;
      aq[j] = (d < DPH) ? (_Float16)qb_[(size_t)qrow * DPH + d] : (_Float16)0.f;
    }
  }

  // register-staged prefetch / LDS commit
  constexpr int kN = CH * SKP / 8;     // uint4 count for K
  constexpr int vN = DPH * 16;         // uint4 count for V
  const int vd = tid >> 4, vq = tid & 15;
  uint4 pk, pv;
  auto prefetch = [&](int cc) {
    if (tid < kN) pk = ((const uint4*)(kb_ + (size_t)cc * CH * SKP))[tid];
    if (tid < vN) pv = ((const uint4*)(vb_ + ((size_t)vd << 10) + cc * CH))[vq];
  };
  auto commit = [&](int pb) {
    if (tid < kN) ((uint4*)(sK + pb * KBUF))[tid] = pk;
    if (tid < vN) *(uint4*)(sVT + (pb * DPH + vd) * VST + vq * 8) = pv;
  };

  prefetch(0);
  commit(0);
  __syncthreads();

  f32x4 Oacc[2] = {{0.f,0.f,0.f,0.f},{0.f,0.f,0.f,0.f}};
  float lsum = 0.f;
  const int de = (col < DPH) ? col : 0;   // clamped: cols >= DPH discarded

#pragma unroll 1
  for (int c = 0; c < nch; ++c) {
    const int p = c & 1;
    if (c + 1 < nch) prefetch(c + 1);

    const _Float16* sKp = sK + p * KBUF;
    const _Float16* sVp = sVT + p * DPH * VST;
    const int keyr = c * CH + grp * 4;   // this lane's reg-dim key base

#pragma unroll
    for (int kt = 0; kt < CH / 16; ++kt) {
      const f16x4 kf = *(const f16x4*)(sKp + (kt * 16 + col) * SKP + grp * 4);
      const int k0 = keyr + kt * 16;
      const f32x4 biasv = {(k0 < cnt) ? 0.f : -100.f,
                           (k0 + 1 < cnt) ? 0.f : -100.f,
                           (k0 + 2 < cnt) ? 0.f : -100.f,
                           (k0 + 3 < cnt) ? 0.f : -100.f};
      const f32x4 S = __builtin_amdgcn_mfma_f32_16x16x16f16(kf, aq, biasv,
                                                            0, 0, 0);
      const float e0 = EXP2(S[0]), e1 = EXP2(S[1]);
      const float e2 = EXP2(S[2]), e3 = EXP2(S[3]);
      lsum += (e0 + e1) + (e2 + e3);
      const f16x4 pf = {(_Float16)e0, (_Float16)e1, (_Float16)e2, (_Float16)e3};
      const f16x4 vf = *(const f16x4*)(sVp + de * VST + kt * 16 + grp * 4);
      Oacc[kt & 1] = __builtin_amdgcn_mfma_f32_16x16x16f16(pf, vf, Oacc[kt & 1],
                                                           0, 0, 0);
    }

    if (c + 1 < nch) commit(p ^ 1);
    __syncthreads();
  }

  // epilogue — ALL cross-lane ops unconditional (r5's NaN was divergence here)
  f32x4 Osum;
#pragma unroll
  for (int r = 0; r < 4; ++r) Osum[r] = Oacc[0][r] + Oacc[1][r];
  float lred = lsum;
  lred += __shfl_xor(lred, 16);
  lred += __shfl_xor(lred, 32);            // lred = l(qrow=col), all lanes
  float lq[4];
#pragma unroll
  for (int r = 0; r < 4; ++r) lq[r] = __shfl(lred, grp * 4 + r);
  if (col < DPH) {
    const int qrow0 = qtile * 16;
#pragma unroll
    for (int r = 0; r < 4; ++r) {
      const int row = qrow0 + grp * 4 + r;
      ctx[(size_t)(b * SLEN + row) * (H * DPH) + h * DPH + col] = Osum[r] / lq[r];
    }
  }
}

__global__ __launch_bounds__(256) void attn_kernel(float* __restrict__ ws)
{
  extern __shared__ char smem[];
  _Float16* hws = (_Float16*)ws;
  const int* cnts = (const int*)(ws + CNT_OFF);
  const int G = gridDim.x;
#pragma unroll 1
  for (int it = blockIdx.x; it < 1728; it += G) {
    if (it < 1024)  // 64 bh * 16 q-strips
      attn_impl<16, 12, 12>(it, ws + Q0_OFF, hws + 2 * (size_t)K0H_OFF,
                            hws + 2 * (size_t)V0T_OFF, cnts, ws + C0_OFF, smem);
    else             // 44 bh * 16 = 704
      attn_impl<11, 6, 8>(it - 1024, ws + Q1_OFF, hws + 2 * (size_t)K1H_OFF,
                          hws + 2 * (size_t)V1T_OFF, cnts + 4, ws + C1_OFF, smem);
  }
}

// ---------------------------------------------------------------------------
// Output projection (f16 MFMA, 3-term hi/lo split => ~fp32 accuracy), with
// register-prefetch staging (r13, unchanged).
// ---------------------------------------------------------------------------
template <int DIM, int NCH>
__device__ void oproj_impl(int bid, const float* __restrict__ Cx,
                           const float* __restrict__ ow, const float* __restrict__ ob,
                           float* __restrict__ out, char* smem)
{
  const int mt64 = bid & 63;
  const int nt = bid >> 6;
  const int row0 = mt64 * 64, col0 = nt * 64;

  _Float16* sAh = (_Float16*)smem;
  _Float16* sAl = sAh + 64 * 72;
  _Float16* sWTh = sAl + 64 * 72;
  _Float16* sWTl = sWTh + 64 * 72;

  const int tid = threadIdx.x;
  const int wv = tid >> 6, lane = tid & 63;

  float2 rA[8], rW[8];
  auto oprefetch = [&](int c) {
    const int kc = c * 64;
#pragma unroll
    for (int t = 0; t < 8; ++t) {
      const int idx = tid + t * 256;
      {
        const int m = idx >> 5, k = (idx & 31) * 2;
        rA[t] = (kc + k < DIM)
                    ? *(const float2*)(Cx + (size_t)(row0 + m) * DIM + kc + k)
                    : make_float2(0.f, 0.f);
      }
      {
        const int k = idx >> 5, n = (idx & 31) * 2;
        rW[t] = (kc + k < DIM && col0 + n < DIM)
                    ? *(const float2*)(ow + (size_t)(kc + k) * DIM + col0 + n)
                    : make_float2(0.f, 0.f);
      }
    }
  };
  auto ocommit = [&]() {
#pragma unroll
    for (int t = 0; t < 8; ++t) {
      const int idx = tid + t * 256;
      {
        const int m = idx >> 5, k = (idx & 31) * 2;
        const _Float16 hx = (_Float16)rA[t].x, hy = (_Float16)rA[t].y;
        *(f16x2*)(sAh + m * 72 + k) = (f16x2){hx, hy};
        *(f16x2*)(sAl + m * 72 + k) =
            (f16x2){(_Float16)(rA[t].x - (float)hx), (_Float16)(rA[t].y - (float)hy)};
      }
      {
        const int k = idx >> 5, n = (idx & 31) * 2;
        const _Float16 hx = (_Float16)rW[t].x, hy = (_Float16)rW[t].y;
        sWTh[n * 72 + k] = hx;
        sWTh[(n + 1) * 72 + k] = hy;
        sWTl[n * 72 + k] = (_Float16)(rW[t].x - (float)hx);
        sWTl[(n + 1) * 72 + k] = (_Float16)(rW[t].y - (float)hy);
      }
    }
  };

  oprefetch(0);

  f32x4 acc[4] = {{0.f,0.f,0.f,0.f},{0.f,0.f,0.f,0.f},{0.f,0.f,0.f,0.f},{0.f,0.f,0.f,0.f}};

  for (int c = 0; c < NCH; ++c) {
    __syncthreads();
    ocommit();
    __syncthreads();
    if (c + 1 < NCH) oprefetch(c + 1);
    mfma_chunk_split(sAh, sAl, sWTh, sWTl, wv, lane, acc);
  }

  const int col = lane & 15, grp = lane >> 4;
  const int cidx = col0 + wv * 16 + col;
  if (cidx < DIM) {
    const float bias = ob[cidx];
#pragma unroll
    for (int mt = 0; mt < 4; ++mt) {
#pragma unroll
      for (int r = 0; r < 4; ++r) {
        const int m = row0 + mt * 16 + grp * 4 + r;
        out[(size_t)m * DIM + cidx] = acc[mt][r] + bias;
      }
    }
  }
}

__global__ __launch_bounds__(256) void oproj_kernel(
    const float* __restrict__ o0w, const float* __restrict__ o0b,
    const float* __restrict__ o1w, const float* __restrict__ o1b,
    float* __restrict__ ws, float* __restrict__ out)
{
  extern __shared__ char smem[];
  const int bid = blockIdx.x;
  if (bid < 192)
    oproj_impl<192, 3>(bid, ws + C0_OFF, o0w, o0b, out, smem);
  else
    oproj_impl<66, 2>(bid - 192, ws + C1_OFF, o1w, o1b, out + OUT0_SIZE, smem);
}

// ---------------------------------------------------------------------------
extern "C" void kernel_launch(void* const* d_in, const int* in_sizes, int n_in,
                              void* d_out, int out_size, void* d_ws, size_t ws_size,
                              hipStream_t stream)
{
  const float* x = (const float*)d_in[0];
  const float* y = (const float*)d_in[1];
  const int* mask0 = (const int*)d_in[2];
  const int* mask1 = (const int*)d_in[3];
  const float* q0w = (const float*)d_in[4];  const float* q0b = (const float*)d_in[5];
  const float* k0w = (const float*)d_in[6];  const float* k0b = (const float*)d_in[7];
  const float* v0w = (const float*)d_in[8];  const float* v0b = (const float*)d_in[9];
  const float* o0w = (const float*)d_in[10]; const float* o0b = (const float*)d_in[11];
  const float* q1w = (const float*)d_in[12]; const float* q1b = (const float*)d_in[13];
  const float* k1w = (const float*)d_in[14]; const float* k1b = (const float*)d_in[15];
  const float* v1w = (const float*)d_in[16]; const float* v1b = (const float*)d_in[17];
  const float* o1w = (const float*)d_in[18]; const float* o1b = (const float*)d_in[19];

  float* ws = (float*)d_ws;
  float* out = (float*)d_out;

  const int qkv_smem = 2 * 64 * 72 * 2 + 64 * 4;   // 18688 B (staging + sSP)
  const int oproj_smem = 4 * 64 * 72 * 2;          // 36864 B
  // attn: sK 2*(128*12+32)*2 = 6272 + sVT 2*12*136*2 = 6528 -> 12800 B
  const int attn_smem = 2 * (128 * 12 + 32) * 2 + 2 * 12 * 136 * 2;

  qkv_kernel<<<960, 256, qkv_smem, stream>>>(x, y, mask0, mask1,
                                             q0w, q0b, k0w, k0b, v0w, v0b,
                                             q1w, q1b, k1w, k1b, v1w, v1b, ws);
  attn_kernel<<<1024, 256, attn_smem, stream>>>(ws);
  oproj_kernel<<<320, 256, oproj_smem, stream>>>(o0w, o0b, o1w, o1b, ws, out);
}